// Round 5
// baseline (601.985 us; speedup 1.0000x reference)
//
#include <hip/hip_runtime.h>
#include <math.h>

#define H_DIM 4096
#define I_DIM 14336
#define HB_DIM 1024
#define SC_K 4300
#define HC_K 716

__device__ __forceinline__ unsigned sortable(float f) {
    unsigned u = __float_as_uint(f);
    return (u & 0x80000000u) ? ~u : (u | 0x80000000u);
}

// dot(x, gate_w[row]) & dot(x, up_w[row]) by one wave; tv[row] = silu(g)*u
__device__ __forceinline__ void compute_tv_row(const float* __restrict__ x,
                                               const float* __restrict__ gate_w,
                                               const float* __restrict__ up_w,
                                               float* __restrict__ tv, int row, int lane) {
    const float* gr = gate_w + (size_t)row * H_DIM;
    const float* ur = up_w + (size_t)row * H_DIM;
    float gs = 0.f, us = 0.f;
#pragma unroll 4
    for (int c = 0; c < H_DIM; c += 256) {
        int cc = c + lane * 4;
        float4 xv = *(const float4*)(x + cc);
        float4 g = *(const float4*)(gr + cc);
        float4 u = *(const float4*)(ur + cc);
        gs += g.x * xv.x + g.y * xv.y + g.z * xv.z + g.w * xv.w;
        us += u.x * xv.x + u.y * xv.y + u.z * xv.z + u.w * xv.w;
    }
#pragma unroll
    for (int o = 32; o >= 1; o >>= 1) {
        gs += __shfl_xor(gs, o);
        us += __shfl_xor(us, o);
    }
    if (lane == 0) {
        float s = gs / (1.f + expf(-gs));
        tv[row] = s * us;
    }
}

// K1: blocks [0,256): h1 = x @ hw1^T (wave per row).
//     blocks [256,1331): gate/up for x_topk rows with claim-dedup.
__global__ __launch_bounds__(256) void k1_h1_gateup(
    const float* __restrict__ x, const float* __restrict__ hw1,
    const int* __restrict__ x_topk, const float* __restrict__ gate_w,
    const float* __restrict__ up_w, float* __restrict__ h1,
    float* __restrict__ tv, int* __restrict__ claim) {
    int wid = threadIdx.x >> 6, lane = threadIdx.x & 63;
    int b = blockIdx.x;
    if (b < 256) {
        int row = b * 4 + wid;  // 0..1023
        const float* mr = hw1 + (size_t)row * H_DIM;
        float s = 0.f;
#pragma unroll 4
        for (int c = 0; c < H_DIM; c += 256) {
            int cc = c + lane * 4;
            float4 m = *(const float4*)(mr + cc);
            float4 v = *(const float4*)(x + cc);
            s += m.x * v.x + m.y * v.y + m.z * v.z + m.w * v.w;
        }
#pragma unroll
        for (int o = 32; o >= 1; o >>= 1) s += __shfl_xor(s, o);
        if (lane == 0) h1[row] = s;
    } else {
        int gw = (b - 256) * 4 + wid;  // 0..4299 (grid sized exactly)
        if (gw < SC_K) {
            int idx = x_topk[gw];
            int won = 0;
            if (lane == 0 && (unsigned)idx < (unsigned)I_DIM)
                won = (atomicExch(&claim[idx], 1) == 0);
            won = __shfl(won, 0);
            if (won) compute_tv_row(x, gate_w, up_w, tv, idx, lane);
        }
    }
}

// K2: h = h1 @ hw2^T (wave per row, 3584 blocks). Last block to finish runs
// the radix select of top HC_K over h -> sel[] (tie: lowest index, matching
// stable jax.lax.top_k). threadFenceReduction pattern — no cooperative launch.
__global__ __launch_bounds__(256) void k2_h_select(
    const float* __restrict__ h1, const float* __restrict__ hw2,
    float* __restrict__ hbuf, int* __restrict__ sel, unsigned* __restrict__ ctr) {
    __shared__ unsigned bins[2048];
    __shared__ unsigned wpart[4];
    __shared__ int s_b, s_above, s_tie, s_last;
    __shared__ int tie_idx[2048];
    int tid = threadIdx.x;
    int wid = tid >> 6, lane = tid & 63;

    {
        int row = blockIdx.x * 4 + wid;
        const float* mr = hw2 + (size_t)row * HB_DIM;
        float s = 0.f;
#pragma unroll
        for (int c = 0; c < HB_DIM; c += 256) {
            int cc = c + lane * 4;
            float4 m = *(const float4*)(mr + cc);
            float4 v = *(const float4*)(h1 + cc);
            s += m.x * v.x + m.y * v.y + m.z * v.z + m.w * v.w;
        }
#pragma unroll
        for (int o = 32; o >= 1; o >>= 1) s += __shfl_xor(s, o);
        if (lane == 0) hbuf[row] = s;
    }
    __threadfence();
    __syncthreads();
    if (tid == 0) {
        unsigned t = atomicAdd(ctr, 1u);
        s_last = (t == gridDim.x - 1);
    }
    __syncthreads();
    if (!s_last) return;
    __threadfence();

    // ---- radix select (256 threads) ----
    int b1 = 0, b2 = 0, b3 = 0, above = 0;
    for (int pass = 0; pass < 3; ++pass) {
        int nb = (pass == 2) ? 1024 : 2048;
        int bpt = nb >> 8;  // 8 or 4 bins per thread
        for (int i = tid; i < nb; i += 256) bins[i] = 0;
        __syncthreads();
        for (int i = tid; i < I_DIM; i += 256) {
            unsigned u = sortable(hbuf[i]);
            bool in_sub = (pass == 0) ||
                          ((pass == 1) ? ((int)(u >> 21) == b1)
                                       : ((int)(u >> 21) == b1 && (int)((u >> 10) & 0x7FF) == b2));
            if (in_sub) {
                unsigned k = (pass == 0) ? (u >> 21)
                           : (pass == 1) ? ((u >> 10) & 0x7FF)
                                         : (u & 0x3FF);
                atomicAdd(&bins[k], 1u);
            }
        }
        __syncthreads();
        unsigned local[8];
        unsigned s = 0;
        for (int j = 0; j < bpt; ++j) { local[j] = bins[tid * bpt + j]; s += local[j]; }
        unsigned incl = s;
#pragma unroll
        for (int o = 1; o < 64; o <<= 1) {
            unsigned v = __shfl_up(incl, o);
            if (lane >= o) incl += v;
        }
        if (lane == 63) wpart[wid] = incl;
        __syncthreads();
        unsigned base = incl - s;
        for (int w2 = 0; w2 < wid; ++w2) base += wpart[w2];
        unsigned total = wpart[0] + wpart[1] + wpart[2] + wpart[3];
        unsigned need = (unsigned)(HC_K - above);
        unsigned P = base;
        for (int j = 0; j < bpt; ++j) {
            unsigned Pm1 = P; P += local[j];
            if (total - P < need && total - Pm1 >= need) {
                s_b = tid * bpt + j; s_above = above + (int)(total - P);
            }
        }
        __syncthreads();
        if (pass == 0) b1 = s_b; else if (pass == 1) b2 = s_b; else b3 = s_b;
        above = s_above;
        __syncthreads();
    }
    unsigned T = ((unsigned)b1 << 21) | ((unsigned)b2 << 10) | (unsigned)b3;
    int need2 = HC_K - above;  // ties to take, lowest index first
    if (tid == 0) s_tie = 0;
    __syncthreads();
    for (int i = tid; i < I_DIM; i += 256) {
        unsigned u = sortable(hbuf[i]);
        if (u > T) sel[i] = 1;
        else if (u == T) {
            int p = atomicAdd(&s_tie, 1);
            if (p < 2048) tie_idx[p] = i;
        }
    }
    __syncthreads();
    int C = s_tie;
    if (C <= 2048) {
        for (int m = tid; m < C; m += 256) {
            int my = tie_idx[m];
            int rank = 0;
            for (int j = 0; j < C; ++j) rank += (tie_idx[j] < my) ? 1 : 0;
            if (rank < need2) sel[my] = 1;
        }
    } else if (tid == 0) {  // degenerate mass-tie fallback (never expected)
        int left = need2;
        for (int i = 0; i < I_DIM && left > 0; ++i)
            if (sortable(hbuf[i]) == T) { sel[i] = 1; --left; }
    }
}

// K3: finish tv — selected-but-unclaimed rows computed, all others zeroed.
__global__ __launch_bounds__(256) void k3_gateup_rest(
    const float* __restrict__ x, const float* __restrict__ gate_w,
    const float* __restrict__ up_w, const int* __restrict__ sel,
    const int* __restrict__ claim, float* __restrict__ tv) {
    int wid = threadIdx.x >> 6, lane = threadIdx.x & 63;
    int row = blockIdx.x * 4 + wid;  // 0..14335
    if (claim[row]) return;  // computed in K1 this call
    if (sel[row]) compute_tv_row(x, gate_w, up_w, tv, row, lane);
    else if (lane == 0) tv[row] = 0.f;
}

// K4: out = down_w @ tv (wave per output row, dense over I).
__global__ __launch_bounds__(256) void k4_down(
    const float* __restrict__ tv, const float* __restrict__ down_w,
    float* __restrict__ out) {
    int wid = threadIdx.x >> 6, lane = threadIdx.x & 63;
    int row = blockIdx.x * 4 + wid;  // 0..4095
    const float* mr = down_w + (size_t)row * I_DIM;
    float s = 0.f;
#pragma unroll 4
    for (int c = 0; c < I_DIM; c += 256) {
        int cc = c + lane * 4;
        float4 m = *(const float4*)(mr + cc);
        float4 v = *(const float4*)(tv + cc);
        s += m.x * v.x + m.y * v.y + m.z * v.z + m.w * v.w;
    }
#pragma unroll
    for (int o = 32; o >= 1; o >>= 1) s += __shfl_xor(s, o);
    if (lane == 0) out[row] = s;
}

extern "C" void kernel_launch(void* const* d_in, const int* in_sizes, int n_in,
                              void* d_out, int out_size, void* d_ws, size_t ws_size,
                              hipStream_t stream) {
    const float* x      = (const float*)d_in[0];
    const int*   x_topk = (const int*)d_in[1];
    const float* gate_w = (const float*)d_in[2];
    const float* up_w   = (const float*)d_in[3];
    const float* down_w = (const float*)d_in[4];
    const float* hw1    = (const float*)d_in[5];
    const float* hw2    = (const float*)d_in[6];
    float* out = (float*)d_out;

    float* ws    = (float*)d_ws;
    float* h1    = ws;                            // 1024
    float* hbuf  = ws + 1024;                     // 14336
    float* tv    = ws + 1024 + I_DIM;             // 14336
    int*   sel   = (int*)(ws + 1024 + 2 * I_DIM); // 14336
    int*   claim = sel + I_DIM;                   // 14336
    unsigned* ctr = (unsigned*)(claim + I_DIM);   // 1

    // zero sel + claim + ctr every call (deterministic across graph replays)
    hipMemsetAsync(sel, 0, (2 * I_DIM + 1) * sizeof(int), stream);

    // K1: h1 GEMV (256 blocks) || gate/up for x_topk rows (1075 blocks)
    k1_h1_gateup<<<256 + (SC_K + 3) / 4, 256, 0, stream>>>(x, hw1, x_topk, gate_w,
                                                           up_w, h1, tv, claim);
    // K2: h GEMV + select in last-finishing block
    k2_h_select<<<I_DIM / 4, 256, 0, stream>>>(h1, hw2, hbuf, sel, ctr);
    // K3: remaining selected rows + zero unneeded tv
    k3_gateup_rest<<<I_DIM / 4, 256, 0, stream>>>(x, gate_w, up_w, sel, claim, tv);
    // K4: dense down-projection
    k4_down<<<H_DIM / 4, 256, 0, stream>>>(tv, down_w, out);
}

// Round 6
// 115.395 us; speedup vs baseline: 5.2167x; 5.2167x over previous
//
#include <hip/hip_runtime.h>
#include <math.h>

#define H_DIM 4096
#define I_DIM 14336
#define HB_DIM 1024
#define SC_K 4300
#define HC_K 716

__device__ __forceinline__ unsigned sortable(float f) {
    unsigned u = __float_as_uint(f);
    return (u & 0x80000000u) ? ~u : (u | 0x80000000u);
}

// dot(x, gate_w[row]) & dot(x, up_w[row]) by one wave; tv[row] = silu(g)*u
__device__ __forceinline__ void compute_tv_row(const float* __restrict__ x,
                                               const float* __restrict__ gate_w,
                                               const float* __restrict__ up_w,
                                               float* __restrict__ tv, int row, int lane) {
    const float* gr = gate_w + (size_t)row * H_DIM;
    const float* ur = up_w + (size_t)row * H_DIM;
    float gs = 0.f, us = 0.f;
#pragma unroll 4
    for (int c = 0; c < H_DIM; c += 256) {
        int cc = c + lane * 4;
        float4 xv = *(const float4*)(x + cc);
        float4 g = *(const float4*)(gr + cc);
        float4 u = *(const float4*)(ur + cc);
        gs += g.x * xv.x + g.y * xv.y + g.z * xv.z + g.w * xv.w;
        us += u.x * xv.x + u.y * xv.y + u.z * xv.z + u.w * xv.w;
    }
#pragma unroll
    for (int o = 32; o >= 1; o >>= 1) {
        gs += __shfl_xor(gs, o);
        us += __shfl_xor(us, o);
    }
    if (lane == 0) {
        float s = gs / (1.f + expf(-gs));
        tv[row] = s * us;
    }
}

// K1: blocks [0,256): h1 = x @ hw1^T (wave per row).
//     blocks [256,...): gate/up for x_topk rows with claim-dedup (distributed
//     atomics — no same-address contention).
__global__ __launch_bounds__(256) void k1_h1_gateup(
    const float* __restrict__ x, const float* __restrict__ hw1,
    const int* __restrict__ x_topk, const float* __restrict__ gate_w,
    const float* __restrict__ up_w, float* __restrict__ h1,
    float* __restrict__ tv, int* __restrict__ claim) {
    int wid = threadIdx.x >> 6, lane = threadIdx.x & 63;
    int b = blockIdx.x;
    if (b < 256) {
        int row = b * 4 + wid;  // 0..1023
        const float* mr = hw1 + (size_t)row * H_DIM;
        float s = 0.f;
#pragma unroll 4
        for (int c = 0; c < H_DIM; c += 256) {
            int cc = c + lane * 4;
            float4 m = *(const float4*)(mr + cc);
            float4 v = *(const float4*)(x + cc);
            s += m.x * v.x + m.y * v.y + m.z * v.z + m.w * v.w;
        }
#pragma unroll
        for (int o = 32; o >= 1; o >>= 1) s += __shfl_xor(s, o);
        if (lane == 0) h1[row] = s;
    } else {
        int gw = (b - 256) * 4 + wid;  // 0..4299
        if (gw < SC_K) {
            int idx = x_topk[gw];
            int won = 0;
            if (lane == 0 && (unsigned)idx < (unsigned)I_DIM)
                won = (atomicExch(&claim[idx], 1) == 0);
            won = __shfl(won, 0);
            if (won) compute_tv_row(x, gate_w, up_w, tv, idx, lane);
        }
    }
}

// K2: h = h1 @ hw2^T (wave per row).
__global__ __launch_bounds__(256) void k2_h(
    const float* __restrict__ h1, const float* __restrict__ hw2,
    float* __restrict__ hbuf) {
    int wid = threadIdx.x >> 6, lane = threadIdx.x & 63;
    int row = blockIdx.x * 4 + wid;
    const float* mr = hw2 + (size_t)row * HB_DIM;
    float s = 0.f;
#pragma unroll
    for (int c = 0; c < HB_DIM; c += 256) {
        int cc = c + lane * 4;
        float4 m = *(const float4*)(mr + cc);
        float4 v = *(const float4*)(h1 + cc);
        s += m.x * v.x + m.y * v.y + m.z * v.z + m.w * v.w;
    }
#pragma unroll
    for (int o = 32; o >= 1; o >>= 1) s += __shfl_xor(s, o);
    if (lane == 0) hbuf[row] = s;
}

// Single-block (1024-thread) radix-select of top HC_K of h: keys cached in
// registers, two-level wave-shfl scans, parallel tie-break (lowest index —
// matches stable jax.lax.top_k). Writes sel[].
__global__ __launch_bounds__(1024) void select_kernel(const float* __restrict__ h,
                                                      int* __restrict__ sel) {
    __shared__ unsigned bins[2048];
    __shared__ unsigned wpart[16];
    __shared__ int s_b, s_above;
    __shared__ int s_tie_cnt;
    __shared__ int tie_idx[2048];
    int tid = threadIdx.x;
    int lane = tid & 63, wid = tid >> 6;

    unsigned key[14];
#pragma unroll
    for (int j = 0; j < 14; ++j) key[j] = sortable(h[j * 1024 + tid]);

    if (tid == 0) s_tie_cnt = 0;

    int b1 = 0, b2 = 0;
    int above = 0;  // elements strictly greater than current prefix

    for (int pass = 0; pass < 3; ++pass) {
        int nb = (pass == 2) ? 1024 : 2048;
        bins[tid] = 0;
        if (nb == 2048) bins[tid + 1024] = 0;
        __syncthreads();
#pragma unroll
        for (int j = 0; j < 14; ++j) {
            unsigned u = key[j];
            bool in_sub = (pass == 0) ||
                          ((pass == 1) ? ((int)(u >> 21) == b1)
                                       : ((int)(u >> 21) == b1 && (int)((u >> 10) & 0x7FF) == b2));
            if (in_sub) {
                unsigned k = (pass == 0) ? (u >> 21)
                           : (pass == 1) ? ((u >> 10) & 0x7FF)
                                         : (u & 0x3FF);
                atomicAdd(&bins[k], 1u);
            }
        }
        __syncthreads();
        // thread t owns bins[2t], bins[2t+1] (zero beyond nb)
        unsigned c0 = (2 * tid < nb) ? bins[2 * tid] : 0u;
        unsigned c1 = (2 * tid + 1 < nb) ? bins[2 * tid + 1] : 0u;
        unsigned s = c0 + c1;
        unsigned incl = s;
#pragma unroll
        for (int o = 1; o < 64; o <<= 1) {
            unsigned v = __shfl_up(incl, o);
            if (lane >= o) incl += v;
        }
        if (lane == 63) wpart[wid] = incl;
        __syncthreads();
        if (wid == 0 && lane < 16) {
            unsigned p = wpart[lane];
#pragma unroll
            for (int o = 1; o < 16; o <<= 1) {
                unsigned v = __shfl_up(p, o, 16);
                if (lane >= o) p += v;
            }
            wpart[lane] = p;
        }
        __syncthreads();
        unsigned total = wpart[15];
        unsigned base = (wid > 0 ? wpart[wid - 1] : 0u) + (incl - s);
        unsigned need = (unsigned)(HC_K - above);
        if (2 * tid < nb) {
            unsigned Pm1 = base, P = base + c0;
            if (total - P < need && total - Pm1 >= need) { s_b = 2 * tid; s_above = above + (int)(total - P); }
        }
        if (2 * tid + 1 < nb) {
            unsigned Pm1 = base + c0, P = base + c0 + c1;
            if (total - P < need && total - Pm1 >= need) { s_b = 2 * tid + 1; s_above = above + (int)(total - P); }
        }
        __syncthreads();
        if (pass == 0) b1 = s_b;
        else if (pass == 1) b2 = s_b;
        above = s_above;
        if (pass == 2) {
            unsigned T = ((unsigned)b1 << 21) | ((unsigned)b2 << 10) | (unsigned)s_b;
            int need2 = HC_K - above;  // ties taken lowest-index-first
            __syncthreads();
#pragma unroll
            for (int j = 0; j < 14; ++j) {
                unsigned u = key[j];
                int i = j * 1024 + tid;
                if (u > T) sel[i] = 1;
                else if (u == T) {
                    int p = atomicAdd(&s_tie_cnt, 1);
                    if (p < 2048) tie_idx[p] = i;
                }
            }
            __syncthreads();
            int C = s_tie_cnt;
            if (C <= 2048) {
                for (int m = tid; m < C; m += 1024) {
                    int my = tie_idx[m];
                    int rank = 0;
                    for (int j = 0; j < C; ++j) rank += (tie_idx[j] < my) ? 1 : 0;
                    if (rank < need2) sel[my] = 1;
                }
            } else if (tid == 0) {  // degenerate mass-tie fallback
                int left = need2;
                for (int i = 0; i < I_DIM && left > 0; ++i)
                    if (sortable(h[i]) == T) { sel[i] = 1; --left; }
            }
        }
        __syncthreads();
    }
}

// K3: finish tv — selected-but-unclaimed rows computed, all others zeroed.
__global__ __launch_bounds__(256) void k3_gateup_rest(
    const float* __restrict__ x, const float* __restrict__ gate_w,
    const float* __restrict__ up_w, const int* __restrict__ sel,
    const int* __restrict__ claim, float* __restrict__ tv) {
    int wid = threadIdx.x >> 6, lane = threadIdx.x & 63;
    int row = blockIdx.x * 4 + wid;  // 0..14335
    if (claim[row]) return;  // computed in K1 this call
    if (sel[row]) compute_tv_row(x, gate_w, up_w, tv, row, lane);
    else if (lane == 0) tv[row] = 0.f;
}

// K4: out = down_w @ tv (wave per output row, dense over I).
__global__ __launch_bounds__(256) void k4_down(
    const float* __restrict__ tv, const float* __restrict__ down_w,
    float* __restrict__ out) {
    int wid = threadIdx.x >> 6, lane = threadIdx.x & 63;
    int row = blockIdx.x * 4 + wid;  // 0..4095
    const float* mr = down_w + (size_t)row * I_DIM;
    float s = 0.f;
#pragma unroll 4
    for (int c = 0; c < I_DIM; c += 256) {
        int cc = c + lane * 4;
        float4 m = *(const float4*)(mr + cc);
        float4 v = *(const float4*)(tv + cc);
        s += m.x * v.x + m.y * v.y + m.z * v.z + m.w * v.w;
    }
#pragma unroll
    for (int o = 32; o >= 1; o >>= 1) s += __shfl_xor(s, o);
    if (lane == 0) out[row] = s;
}

extern "C" void kernel_launch(void* const* d_in, const int* in_sizes, int n_in,
                              void* d_out, int out_size, void* d_ws, size_t ws_size,
                              hipStream_t stream) {
    const float* x      = (const float*)d_in[0];
    const int*   x_topk = (const int*)d_in[1];
    const float* gate_w = (const float*)d_in[2];
    const float* up_w   = (const float*)d_in[3];
    const float* down_w = (const float*)d_in[4];
    const float* hw1    = (const float*)d_in[5];
    const float* hw2    = (const float*)d_in[6];
    float* out = (float*)d_out;

    float* ws    = (float*)d_ws;
    float* h1    = ws;                            // 1024
    float* hbuf  = ws + 1024;                     // 14336
    float* tv    = ws + 1024 + I_DIM;             // 14336
    int*   sel   = (int*)(ws + 1024 + 2 * I_DIM); // 14336
    int*   claim = sel + I_DIM;                   // 14336

    // zero sel + claim every call (deterministic across graph replays)
    hipMemsetAsync(sel, 0, 2 * I_DIM * sizeof(int), stream);

    // K1: h1 GEMV (256 blocks) || gate/up for x_topk rows (1075 blocks)
    k1_h1_gateup<<<256 + (SC_K + 3) / 4, 256, 0, stream>>>(x, hw1, x_topk, gate_w,
                                                           up_w, h1, tv, claim);
    // K2: h GEMV
    k2_h<<<I_DIM / 4, 256, 0, stream>>>(h1, hw2, hbuf);
    // K2b: top-716 select (single block, 1024 threads, keys in registers)
    select_kernel<<<1, 1024, 0, stream>>>(hbuf, sel);
    // K3: remaining selected rows + zero unneeded tv
    k3_gateup_rest<<<I_DIM / 4, 256, 0, stream>>>(x, gate_w, up_w, sel, claim, tv);
    // K4: dense down-projection
    k4_down<<<H_DIM / 4, 256, 0, stream>>>(tv, down_w, out);
}

// Round 7
// 103.659 us; speedup vs baseline: 5.8074x; 1.1132x over previous
//
#include <hip/hip_runtime.h>
#include <math.h>

#define H_DIM 4096
#define I_DIM 14336
#define HB_DIM 1024
#define SC_K 4300
#define HC_K 716

__device__ __forceinline__ unsigned sortable(float f) {
    unsigned u = __float_as_uint(f);
    return (u & 0x80000000u) ? ~u : (u | 0x80000000u);
}

// dot(x, gate_w[row]) & dot(x, up_w[row]) by one wave; tv[row] = silu(g)*u
__device__ __forceinline__ void compute_tv_row(const float* __restrict__ x,
                                               const float* __restrict__ gate_w,
                                               const float* __restrict__ up_w,
                                               float* __restrict__ tv, int row, int lane) {
    const float* gr = gate_w + (size_t)row * H_DIM;
    const float* ur = up_w + (size_t)row * H_DIM;
    float gs = 0.f, us = 0.f;
#pragma unroll 4
    for (int c = 0; c < H_DIM; c += 256) {
        int cc = c + lane * 4;
        float4 xv = *(const float4*)(x + cc);
        float4 g = *(const float4*)(gr + cc);
        float4 u = *(const float4*)(ur + cc);
        gs += g.x * xv.x + g.y * xv.y + g.z * xv.z + g.w * xv.w;
        us += u.x * xv.x + u.y * xv.y + u.z * xv.z + u.w * xv.w;
    }
#pragma unroll
    for (int o = 32; o >= 1; o >>= 1) {
        gs += __shfl_xor(gs, o);
        us += __shfl_xor(us, o);
    }
    if (lane == 0) {
        float s = gs / (1.f + expf(-gs));
        tv[row] = s * us;
    }
}

// K1: blocks [0,256): h1 = x @ hw1^T (wave per row).
//     blocks [256,1331): gate/up for ALL x_topk entries — duplicates write
//     bitwise-identical tv values (benign race), so no dedup/atomics needed.
__global__ __launch_bounds__(256) void k1_h1_gateup(
    const float* __restrict__ x, const float* __restrict__ hw1,
    const int* __restrict__ x_topk, const float* __restrict__ gate_w,
    const float* __restrict__ up_w, float* __restrict__ h1,
    float* __restrict__ tv) {
    int wid = threadIdx.x >> 6, lane = threadIdx.x & 63;
    int b = blockIdx.x;
    if (b < 256) {
        int row = b * 4 + wid;  // 0..1023
        const float* mr = hw1 + (size_t)row * H_DIM;
        float s = 0.f;
#pragma unroll 4
        for (int c = 0; c < H_DIM; c += 256) {
            int cc = c + lane * 4;
            float4 m = *(const float4*)(mr + cc);
            float4 v = *(const float4*)(x + cc);
            s += m.x * v.x + m.y * v.y + m.z * v.z + m.w * v.w;
        }
#pragma unroll
        for (int o = 32; o >= 1; o >>= 1) s += __shfl_xor(s, o);
        if (lane == 0) h1[row] = s;
    } else {
        int gw = (b - 256) * 4 + wid;  // 0..4299 (grid sized exactly)
        if (gw < SC_K) {
            int idx = x_topk[gw];
            if ((unsigned)idx < (unsigned)I_DIM)
                compute_tv_row(x, gate_w, up_w, tv, idx, lane);
        }
    }
}

// K2: h = h1 @ hw2^T (wave per row).
__global__ __launch_bounds__(256) void k2_h(
    const float* __restrict__ h1, const float* __restrict__ hw2,
    float* __restrict__ hbuf) {
    int wid = threadIdx.x >> 6, lane = threadIdx.x & 63;
    int row = blockIdx.x * 4 + wid;
    const float* mr = hw2 + (size_t)row * HB_DIM;
    float s = 0.f;
#pragma unroll
    for (int c = 0; c < HB_DIM; c += 256) {
        int cc = c + lane * 4;
        float4 m = *(const float4*)(mr + cc);
        float4 v = *(const float4*)(h1 + cc);
        s += m.x * v.x + m.y * v.y + m.z * v.z + m.w * v.w;
    }
#pragma unroll
    for (int o = 32; o >= 1; o >>= 1) s += __shfl_xor(s, o);
    if (lane == 0) hbuf[row] = s;
}

// Single-block (1024-thread) radix-select of top HC_K of h. Keys in registers,
// two-level wave-shfl scans, tie-break toward lowest index (stable top_k).
// Outputs: tv[i]=0 for rows neither topk nor selected; compact residual list
// (selected && !topk) + count. No global flag arrays, no pre-zeroing needed.
__global__ __launch_bounds__(1024) void select_kernel(
    const float* __restrict__ h, const int* __restrict__ x_topk,
    float* __restrict__ tv, int* __restrict__ rlist, int* __restrict__ rcount) {
    __shared__ unsigned bins[2048];
    __shared__ unsigned wpart[16];
    __shared__ unsigned bitT[448], bitS[448];  // 14336 bits each
    __shared__ int s_b, s_above, s_tie_cnt, s_rc;
    __shared__ int tie_idx[2048];
    int tid = threadIdx.x;
    int lane = tid & 63, wid = tid >> 6;

    unsigned key[14];
#pragma unroll
    for (int j = 0; j < 14; ++j) key[j] = sortable(h[j * 1024 + tid]);

    if (tid < 448) { bitT[tid] = 0; bitS[tid] = 0; }
    if (tid == 0) { s_tie_cnt = 0; s_rc = 0; }
    __syncthreads();

    // x_topk membership bitmap
    for (int k = tid; k < SC_K; k += 1024) {
        int idx = x_topk[k];
        if ((unsigned)idx < (unsigned)I_DIM) atomicOr(&bitT[idx >> 5], 1u << (idx & 31));
    }

    int b1 = 0, b2 = 0;
    int above = 0;  // elements strictly greater than current prefix
    unsigned T = 0;
    int need2 = 0;

    for (int pass = 0; pass < 3; ++pass) {
        int nb = (pass == 2) ? 1024 : 2048;
        bins[tid] = 0;
        if (nb == 2048) bins[tid + 1024] = 0;
        __syncthreads();
#pragma unroll
        for (int j = 0; j < 14; ++j) {
            unsigned u = key[j];
            bool in_sub = (pass == 0) ||
                          ((pass == 1) ? ((int)(u >> 21) == b1)
                                       : ((int)(u >> 21) == b1 && (int)((u >> 10) & 0x7FF) == b2));
            if (in_sub) {
                unsigned k = (pass == 0) ? (u >> 21)
                           : (pass == 1) ? ((u >> 10) & 0x7FF)
                                         : (u & 0x3FF);
                atomicAdd(&bins[k], 1u);
            }
        }
        __syncthreads();
        // thread t owns bins[2t], bins[2t+1] (zero beyond nb)
        unsigned c0 = (2 * tid < nb) ? bins[2 * tid] : 0u;
        unsigned c1 = (2 * tid + 1 < nb) ? bins[2 * tid + 1] : 0u;
        unsigned s = c0 + c1;
        unsigned incl = s;
#pragma unroll
        for (int o = 1; o < 64; o <<= 1) {
            unsigned v = __shfl_up(incl, o);
            if (lane >= o) incl += v;
        }
        if (lane == 63) wpart[wid] = incl;
        __syncthreads();
        if (wid == 0 && lane < 16) {
            unsigned p = wpart[lane];
#pragma unroll
            for (int o = 1; o < 16; o <<= 1) {
                unsigned v = __shfl_up(p, o, 16);
                if (lane >= o) p += v;
            }
            wpart[lane] = p;
        }
        __syncthreads();
        unsigned total = wpart[15];
        unsigned base = (wid > 0 ? wpart[wid - 1] : 0u) + (incl - s);
        unsigned need = (unsigned)(HC_K - above);
        if (2 * tid < nb) {
            unsigned Pm1 = base, P = base + c0;
            if (total - P < need && total - Pm1 >= need) { s_b = 2 * tid; s_above = above + (int)(total - P); }
        }
        if (2 * tid + 1 < nb) {
            unsigned Pm1 = base + c0, P = base + c0 + c1;
            if (total - P < need && total - Pm1 >= need) { s_b = 2 * tid + 1; s_above = above + (int)(total - P); }
        }
        __syncthreads();
        if (pass == 0) b1 = s_b;
        else if (pass == 1) b2 = s_b;
        above = s_above;
        if (pass == 2) {
            T = ((unsigned)b1 << 21) | ((unsigned)b2 << 10) | (unsigned)s_b;
            need2 = HC_K - above;
        }
        __syncthreads();
    }

    // mark selected rows in bitS: strictly-above + lowest-index ties
#pragma unroll
    for (int j = 0; j < 14; ++j) {
        unsigned u = key[j];
        int i = j * 1024 + tid;
        if (u > T) atomicOr(&bitS[i >> 5], 1u << (i & 31));
        else if (u == T) {
            int p = atomicAdd(&s_tie_cnt, 1);
            if (p < 2048) tie_idx[p] = i;
        }
    }
    __syncthreads();
    int C = s_tie_cnt;
    if (C <= 2048) {
        for (int m = tid; m < C; m += 1024) {
            int my = tie_idx[m];
            int rank = 0;
            for (int j = 0; j < C; ++j) rank += (tie_idx[j] < my) ? 1 : 0;
            if (rank < need2) atomicOr(&bitS[my >> 5], 1u << (my & 31));
        }
    } else if (tid == 0) {  // degenerate mass-tie fallback (never expected)
        int left = need2;
        for (int i = 0; i < I_DIM && left > 0; ++i)
            if (sortable(h[i]) == T) { atomicOr(&bitS[i >> 5], 1u << (i & 31)); --left; }
    }
    __syncthreads();

    // emit: zero tv for untouched rows; residual list = selected && !topk
#pragma unroll
    for (int j = 0; j < 14; ++j) {
        int i = j * 1024 + tid;
        bool t = (bitT[i >> 5] >> (i & 31)) & 1u;
        bool sl = (bitS[i >> 5] >> (i & 31)) & 1u;
        if (!t) {
            if (sl) {
                int p = atomicAdd(&s_rc, 1);
                rlist[p] = i;
            } else {
                tv[i] = 0.f;
            }
        }
    }
    __syncthreads();
    if (tid == 0) *rcount = s_rc;
}

// K3: residual gate/up rows from compact list (<=716 entries).
__global__ __launch_bounds__(256) void k3_residual(
    const float* __restrict__ x, const float* __restrict__ gate_w,
    const float* __restrict__ up_w, const int* __restrict__ rlist,
    const int* __restrict__ rcount, float* __restrict__ tv) {
    int wid = threadIdx.x >> 6, lane = threadIdx.x & 63;
    int gw = blockIdx.x * 4 + wid;
    if (gw < *rcount) compute_tv_row(x, gate_w, up_w, tv, rlist[gw], lane);
}

// K4: out = down_w @ tv (wave per output row, dense over I).
__global__ __launch_bounds__(256) void k4_down(
    const float* __restrict__ tv, const float* __restrict__ down_w,
    float* __restrict__ out) {
    int wid = threadIdx.x >> 6, lane = threadIdx.x & 63;
    int row = blockIdx.x * 4 + wid;  // 0..4095
    const float* mr = down_w + (size_t)row * I_DIM;
    float s = 0.f;
#pragma unroll 4
    for (int c = 0; c < I_DIM; c += 256) {
        int cc = c + lane * 4;
        float4 m = *(const float4*)(mr + cc);
        float4 v = *(const float4*)(tv + cc);
        s += m.x * v.x + m.y * v.y + m.z * v.z + m.w * v.w;
    }
#pragma unroll
    for (int o = 32; o >= 1; o >>= 1) s += __shfl_xor(s, o);
    if (lane == 0) out[row] = s;
}

extern "C" void kernel_launch(void* const* d_in, const int* in_sizes, int n_in,
                              void* d_out, int out_size, void* d_ws, size_t ws_size,
                              hipStream_t stream) {
    const float* x      = (const float*)d_in[0];
    const int*   x_topk = (const int*)d_in[1];
    const float* gate_w = (const float*)d_in[2];
    const float* up_w   = (const float*)d_in[3];
    const float* down_w = (const float*)d_in[4];
    const float* hw1    = (const float*)d_in[5];
    const float* hw2    = (const float*)d_in[6];
    float* out = (float*)d_out;

    float* ws    = (float*)d_ws;
    float* h1    = ws;                             // 1024
    float* hbuf  = ws + 1024;                      // 14336
    float* tv    = ws + 1024 + I_DIM;              // 14336
    int*   rlist = (int*)(ws + 1024 + 2 * I_DIM);  // 716 (+pad)
    int*   rcount = rlist + 768;                   // 1

    // K1: h1 GEMV (256 blocks) || gate/up for all x_topk entries (1075 blocks)
    k1_h1_gateup<<<256 + (SC_K + 3) / 4, 256, 0, stream>>>(x, hw1, x_topk, gate_w,
                                                           up_w, h1, tv);
    // K2: h GEMV
    k2_h<<<I_DIM / 4, 256, 0, stream>>>(h1, hw2, hbuf);
    // K2b: top-716 select -> tv zeros + residual list (single block)
    select_kernel<<<1, 1024, 0, stream>>>(hbuf, x_topk, tv, rlist, rcount);
    // K3: residual gate/up rows (list-driven, 179 blocks)
    k3_residual<<<(HC_K + 3) / 4, 256, 0, stream>>>(x, gate_w, up_w, rlist, rcount, tv);
    // K4: dense down-projection
    k4_down<<<H_DIM / 4, 256, 0, stream>>>(tv, down_w, out);
}